// Round 14
// baseline (51.218 us; speedup 1.0000x reference)
//
#include <hip/hip_runtime.h>
#include <math.h>
#include <stdint.h>

// GE2E loss on MI355X — 3-kernel pipeline. No memsets, no fences, no atomics.
// out = sum_k counts[k]*log(sum_j exp(S[j,k])) - sum_i logit_self[i]
// Logits <= w*1+b = 5 -> exp without max-subtraction is safe in fp32.
// K1 (512 thr, block=class): ballot-gather centroid, dual-row mask walk.
//     (512 thr, NOT 1024: launch_bounds(1024) caps VGPR at 64 -> spills; needs ~88.)
// K2 (512 thr): MFMA GEMM ebf @ csum^T (BM=64, BN=256, BK=64, dbuf gload_lds).
// K3 (1 block, 1024 thr): coalesced colpart reduce + counts*log - selfpart -> out.
// Self logit: u = csum_y - e; dot(e,u)=dot-1; |u|^2 = nsq - 2*dot + 1.

typedef __attribute__((ext_vector_type(8))) short bf16x8;
typedef __attribute__((ext_vector_type(4))) float f32x4;
struct alignas(16) US8 { unsigned short u[8]; };

__device__ inline float waveReduceSum(float v) {
#pragma unroll
    for (int m = 32; m >= 1; m >>= 1) v += __shfl_xor(v, m, 64);
    return v;
}
__device__ inline void waveReduceSum2(float& a, float& b) {
#pragma unroll
    for (int m = 32; m >= 1; m >>= 1) {
        float ta = __shfl_xor(a, m, 64);
        float tb = __shfl_xor(b, m, 64);
        a += ta; b += tb;
    }
}
__device__ inline unsigned short f2bf(float f) {
    uint32_t u = __float_as_uint(f);
    return (unsigned short)((u + 0x7FFFu + ((u >> 16) & 1u)) >> 16);
}
__device__ inline void gload_lds16(const void* g, void* l) {
    __builtin_amdgcn_global_load_lds(
        (const __attribute__((address_space(1))) uint32_t*)g,
        (__attribute__((address_space(3))) uint32_t*)l, 16, 0, 0);
}

// --- K1: fused normalize + per-class centroid (block per class, 8 waves) ---
__global__ __launch_bounds__(512) void k_centroid(
        const float* __restrict__ emb, const int* __restrict__ y,
        const float* __restrict__ wptr, unsigned short* __restrict__ ebf,
        unsigned short* __restrict__ csum_bf, float* __restrict__ normsq,
        float* __restrict__ colscale, int* __restrict__ counts, int N) {
    __shared__ float part[8][512];
    __shared__ float red[512];
    __shared__ int cnts[8];
    int c = blockIdx.x;
    int tid = threadIdx.x, l = tid & 63, w = tid >> 6;
    int chunk = N >> 3;                       // rows per wave (2048)
    float facc[8] = {0.f, 0.f, 0.f, 0.f, 0.f, 0.f, 0.f, 0.f};
    int cnt = 0;
    int iend = (w + 1) * chunk;
    int i0 = w * chunk;
    int4 y4 = *reinterpret_cast<const int4*>(y + i0 + l * 4);
    for (; i0 < iend; i0 += 256) {
        int4 cy = y4;
        if (i0 + 256 < iend)                  // prefetch next y tile
            y4 = *reinterpret_cast<const int4*>(y + i0 + 256 + l * 4);
#pragma unroll
        for (int comp = 0; comp < 4; ++comp) {
            int yv = (comp == 0) ? cy.x : (comp == 1) ? cy.y : (comp == 2) ? cy.z : cy.w;
            unsigned long long m = __ballot(yv == c);
            cnt += (int)__popcll(m);
            while (m) {                        // wave-uniform mask; pop 2 rows/iter
                int b0 = __builtin_ctzll(m); m &= m - 1;
                int rA = i0 + 4 * b0 + comp;
                const float4* pA = reinterpret_cast<const float4*>(emb + (size_t)rA * 512);
                if (m) {
                    int b1 = __builtin_ctzll(m); m &= m - 1;
                    int rB = i0 + 4 * b1 + comp;
                    const float4* pB = reinterpret_cast<const float4*>(emb + (size_t)rB * 512);
                    float4 a0 = pA[l * 2], a1 = pA[l * 2 + 1];   // both rows' loads
                    float4 c0 = pB[l * 2], c1 = pB[l * 2 + 1];   // issue together
                    float sA = a0.x * a0.x + a0.y * a0.y + a0.z * a0.z + a0.w * a0.w
                             + a1.x * a1.x + a1.y * a1.y + a1.z * a1.z + a1.w * a1.w;
                    float sB = c0.x * c0.x + c0.y * c0.y + c0.z * c0.z + c0.w * c0.w
                             + c1.x * c1.x + c1.y * c1.y + c1.z * c1.z + c1.w * c1.w;
                    waveReduceSum2(sA, sB);
                    float invA = 1.0f / fmaxf(sqrtf(sA), 1e-12f);
                    float invB = 1.0f / fmaxf(sqrtf(sB), 1e-12f);
                    float eA0 = a0.x * invA, eA1 = a0.y * invA, eA2 = a0.z * invA, eA3 = a0.w * invA;
                    float eA4 = a1.x * invA, eA5 = a1.y * invA, eA6 = a1.z * invA, eA7 = a1.w * invA;
                    float eB0 = c0.x * invB, eB1 = c0.y * invB, eB2 = c0.z * invB, eB3 = c0.w * invB;
                    float eB4 = c1.x * invB, eB5 = c1.y * invB, eB6 = c1.z * invB, eB7 = c1.w * invB;
                    US8 tA, tB;
                    tA.u[0] = f2bf(eA0); tA.u[1] = f2bf(eA1); tA.u[2] = f2bf(eA2); tA.u[3] = f2bf(eA3);
                    tA.u[4] = f2bf(eA4); tA.u[5] = f2bf(eA5); tA.u[6] = f2bf(eA6); tA.u[7] = f2bf(eA7);
                    tB.u[0] = f2bf(eB0); tB.u[1] = f2bf(eB1); tB.u[2] = f2bf(eB2); tB.u[3] = f2bf(eB3);
                    tB.u[4] = f2bf(eB4); tB.u[5] = f2bf(eB5); tB.u[6] = f2bf(eB6); tB.u[7] = f2bf(eB7);
                    *reinterpret_cast<US8*>(ebf + (size_t)rA * 512 + l * 8) = tA;
                    *reinterpret_cast<US8*>(ebf + (size_t)rB * 512 + l * 8) = tB;
                    facc[0] += eA0 + eB0; facc[1] += eA1 + eB1;
                    facc[2] += eA2 + eB2; facc[3] += eA3 + eB3;
                    facc[4] += eA4 + eB4; facc[5] += eA5 + eB5;
                    facc[6] += eA6 + eB6; facc[7] += eA7 + eB7;
                } else {
                    float4 a0 = pA[l * 2], a1 = pA[l * 2 + 1];
                    float s = a0.x * a0.x + a0.y * a0.y + a0.z * a0.z + a0.w * a0.w
                            + a1.x * a1.x + a1.y * a1.y + a1.z * a1.z + a1.w * a1.w;
                    s = waveReduceSum(s);
                    float inv = 1.0f / fmaxf(sqrtf(s), 1e-12f);
                    float e0 = a0.x * inv, e1 = a0.y * inv, e2 = a0.z * inv, e3 = a0.w * inv;
                    float e4 = a1.x * inv, e5 = a1.y * inv, e6 = a1.z * inv, e7 = a1.w * inv;
                    US8 t;
                    t.u[0] = f2bf(e0); t.u[1] = f2bf(e1); t.u[2] = f2bf(e2); t.u[3] = f2bf(e3);
                    t.u[4] = f2bf(e4); t.u[5] = f2bf(e5); t.u[6] = f2bf(e6); t.u[7] = f2bf(e7);
                    *reinterpret_cast<US8*>(ebf + (size_t)rA * 512 + l * 8) = t;
                    facc[0] += e0; facc[1] += e1; facc[2] += e2; facc[3] += e3;
                    facc[4] += e4; facc[5] += e5; facc[6] += e6; facc[7] += e7;
                }
            }
        }
    }
    *reinterpret_cast<float4*>(&part[w][l * 8]) =
        make_float4(facc[0], facc[1], facc[2], facc[3]);
    *reinterpret_cast<float4*>(&part[w][l * 8 + 4]) =
        make_float4(facc[4], facc[5], facc[6], facc[7]);
    if (l == 0) cnts[w] = cnt;
    __syncthreads();
    float s = part[0][tid] + part[1][tid] + part[2][tid] + part[3][tid]
            + part[4][tid] + part[5][tid] + part[6][tid] + part[7][tid];
    csum_bf[(size_t)c * 512 + tid] = f2bf(s);
    red[tid] = s * s;
    __syncthreads();
    for (int o = 256; o >= 1; o >>= 1) {
        if (tid < o) red[tid] += red[tid + o];
        __syncthreads();
    }
    if (tid == 0) {
        int ct = cnts[0] + cnts[1] + cnts[2] + cnts[3]
               + cnts[4] + cnts[5] + cnts[6] + cnts[7];
        counts[c] = ct;
        float nsq = red[0];
        normsq[c] = nsq;
        colscale[c] = wptr[0] / fmaxf(sqrtf(nsq), (float)ct * 1e-8f);
    }
}

// --- K2: GEMM (64 rows x 256 cols per block, 8 waves, dbuf gload_lds) ---
#define NKT 8

__global__ __launch_bounds__(512) void k_gemm(
        const unsigned short* __restrict__ ebf, const unsigned short* __restrict__ csum_bf,
        const int* __restrict__ y, const float* __restrict__ colscale,
        const float* __restrict__ normsq, const int* __restrict__ counts,
        const float* __restrict__ wptr, const float* __restrict__ bptr,
        float* __restrict__ colpart, float* __restrict__ selfpart, int C) {
    __shared__ __align__(16) unsigned short As[2][8 * 512];     // 2 x 8 KB
    __shared__ __align__(16) unsigned short Bs[2][32 * 512];    // 2 x 32 KB
    __shared__ float colsum[256];
    __shared__ float selfred[8];

    const int tid = threadIdx.x;
    const int l = tid & 63;
    const int w = tid >> 6;
    const int bx = blockIdx.x;
    const int r0 = bx * 64;
    const int rsub = l >> 2;
    const int kcs = ((l & 3) ^ ((l >> 3) & 3)) * 8;

    const unsigned short* srcA = ebf + (size_t)(r0 + (w & 3) * 16 + rsub) * 512
                               + (w >> 2) * 32 + kcs;
    const unsigned short* srcB[4];
#pragma unroll
    for (int i = 0; i < 4; ++i) {
        int st = w * 4 + i;
        srcB[i] = csum_bf + (size_t)((st & 15) * 16 + rsub) * 512 + (st >> 4) * 32 + kcs;
    }
    const int fro = (l & 15) * 32 + (((l >> 4) ^ ((l >> 1) & 3)) * 8);

    f32x4 acc[4][2];
#pragma unroll
    for (int m = 0; m < 4; ++m)
#pragma unroll
        for (int n = 0; n < 2; ++n) acc[m][n] = (f32x4){0.f, 0.f, 0.f, 0.f};

    gload_lds16(srcA, &As[0][w * 512]);
#pragma unroll
    for (int i = 0; i < 4; ++i) gload_lds16(srcB[i], &Bs[0][(w * 4 + i) * 512]);
    __syncthreads();

    int cur = 0;
    for (int kt = 0; kt < NKT; ++kt) {
        if (kt + 1 < NKT) {
            gload_lds16(srcA + (kt + 1) * 64, &As[cur ^ 1][w * 512]);
#pragma unroll
            for (int i = 0; i < 4; ++i)
                gload_lds16(srcB[i] + (kt + 1) * 64, &Bs[cur ^ 1][(w * 4 + i) * 512]);
        }
#pragma unroll
        for (int h = 0; h < 2; ++h) {
            bf16x8 af[4];
#pragma unroll
            for (int m = 0; m < 4; ++m)
                af[m] = *reinterpret_cast<const bf16x8*>(&As[cur][(h * 4 + m) * 512 + fro]);
#pragma unroll
            for (int n = 0; n < 2; ++n) {
                bf16x8 bv = *reinterpret_cast<const bf16x8*>(
                    &Bs[cur][(h * 16 + w * 2 + n) * 512 + fro]);
#pragma unroll
                for (int m = 0; m < 4; ++m)
                    acc[m][n] = __builtin_amdgcn_mfma_f32_16x16x32_bf16(af[m], bv, acc[m][n], 0, 0, 0);
            }
        }
        __syncthreads();
        cur ^= 1;
    }

    // epilogue: C/D layout col=lane&15, row=(lane>>4)*4+j; wave w -> cols w*32..+31
    float bv = bptr[0], wv = wptr[0];
    int lcol = l & 15, lrow4 = (l >> 4) * 4;
    float cs[2], nsq[2], cm1[2]; int cls[2];
#pragma unroll
    for (int n = 0; n < 2; ++n) {
        int c = w * 32 + n * 16 + lcol;
        cls[n] = c; cs[n] = colscale[c]; nsq[n] = normsq[c];
        cm1[n] = (float)(counts[c] - 1);
    }
    float colacc[2] = {0.f, 0.f};
    float selfacc = 0.f;
#pragma unroll
    for (int m = 0; m < 4; ++m) {
#pragma unroll
        for (int j = 0; j < 4; ++j) {
            int row = r0 + m * 16 + lrow4 + j;
            int yc = y[row];
#pragma unroll
            for (int n = 0; n < 2; ++n) {
                float dot = acc[m][n][j];
                float logit;
                if (yc == cls[n]) {
                    float un2 = fmaxf(nsq[n] - 2.f * dot + 1.f, 0.f);
                    float denom = fmaxf(sqrtf(un2), cm1[n] * 1e-8f);
                    logit = wv * (dot - 1.f) / denom + bv;
                    selfacc += logit;
                } else {
                    logit = dot * cs[n] + bv;
                }
                colacc[n] += __expf(logit);
            }
        }
    }
#pragma unroll
    for (int n = 0; n < 2; ++n) {
        float v = colacc[n];
        v += __shfl_xor(v, 16, 64);
        v += __shfl_xor(v, 32, 64);
        colacc[n] = v;
    }
    selfacc = waveReduceSum(selfacc);
    if (l < 16) {
#pragma unroll
        for (int n = 0; n < 2; ++n) colsum[w * 32 + n * 16 + l] = colacc[n];
    }
    if (l == 0) selfred[w] = selfacc;
    __syncthreads();
    if (tid < 256)
        colpart[(size_t)bx * 256 + tid] = colsum[tid];
    if (tid == 0)
        selfpart[bx] = selfred[0] + selfred[1] + selfred[2] + selfred[3]
                     + selfred[4] + selfred[5] + selfred[6] + selfred[7];
}

// --- K3: single-block finalize: coalesced colpart reduce + log + selfpart ---
__global__ __launch_bounds__(1024) void k_finalize(
        const float* __restrict__ colpart, const int* __restrict__ counts,
        const float* __restrict__ selfpart, float* __restrict__ out, int nbx, int C) {
    __shared__ float part2[1024];
    __shared__ float red[256];
    int tid = threadIdx.x;
    int c = tid & 255;
    int r0 = tid >> 8;                         // 0..3
    float s = 0.f;
    for (int i = r0; i < nbx; i += 4)          // coalesced: wave reads 256-float rows
        s += colpart[(size_t)i * 256 + c];
    part2[tid] = s;
    __syncthreads();
    if (tid < 256) {
        float csum = part2[tid] + part2[tid + 256] + part2[tid + 512] + part2[tid + 768];
        float v = (float)counts[tid] * logf(csum);
        for (int i = tid; i < nbx; i += 256) v -= selfpart[i];
        red[tid] = v;
    }
    __syncthreads();
    for (int o = 128; o >= 1; o >>= 1) {
        if (tid < o) red[tid] += red[tid + o];
        __syncthreads();
    }
    if (tid == 0) out[0] = red[0];
}

extern "C" void kernel_launch(void* const* d_in, const int* in_sizes, int n_in,
                              void* d_out, int out_size, void* d_ws, size_t ws_size,
                              hipStream_t stream) {
    const float* emb  = (const float*)d_in[0];
    const int*   y    = (const int*)d_in[1];
    const float* wptr = (const float*)d_in[2];
    const float* bptr = (const float*)d_in[3];
    float* out = (float*)d_out;
    int N = in_sizes[1];                      // 16384
    const int C = 256;
    int nbx = N / 64;                         // 256

    unsigned short* ebf     = (unsigned short*)d_ws;                 // N*512 bf16
    unsigned short* csum_bf = ebf + (size_t)N * 512;                 // C*512 bf16
    float* colpart  = (float*)(csum_bf + (size_t)C * 512);           // nbx*C
    float* selfpart = colpart + (size_t)nbx * C;                     // nbx
    float* normsq   = selfpart + nbx;                                // C
    float* colscale = normsq + C;                                    // C
    int*   counts   = (int*)(colscale + C);                          // C

    k_centroid<<<C, 512, 0, stream>>>(emb, y, wptr, ebf, csum_bf, normsq,
                                      colscale, counts, N);
    k_gemm    <<<nbx, 512, 0, stream>>>(ebf, csum_bf, y, colscale, normsq, counts,
                                        wptr, bptr, colpart, selfpart, C);
    k_finalize<<<1, 1024, 0, stream>>>(colpart, counts, selfpart, out, nbx, C);
}

// Round 15
// 35.640 us; speedup vs baseline: 1.4371x; 1.4371x over previous
//
#include <hip/hip_runtime.h>
#include <math.h>
#include <stdint.h>

// GE2E loss on MI355X — 4-kernel pipeline. No memsets, no fences, no atomics.
// out = sum_k counts[k]*log(sum_j exp(S[j,k])) - sum_i logit_self[i]
// Logits <= w*1+b = 5 -> exp without max-subtraction is safe in fp32.
// K1 (1024 thr, block=class): ballot-gather centroid, single-pop walk
//     (16 waves/CU for latency hiding; single-pop keeps VGPR < 64 cap).
// K2 (512 thr): MFMA GEMM ebf @ csum^T (BM=64, BN=256, BK=64, dbuf gload_lds).
// K3 (256 blk x 64 thr): per-class colpart reduce -> contrib[c].
// K4 (1 blk): sum contribs - selfparts -> out.
// Self logit: u = csum_y - e; dot(e,u)=dot-1; |u|^2 = nsq - 2*dot + 1.
// LESSON (r5/r14): never single-block-reduce the 256KB colpart — XCD-scattered
// lines on one CU cost ~13us. Spread across 256 blocks.

typedef __attribute__((ext_vector_type(8))) short bf16x8;
typedef __attribute__((ext_vector_type(4))) float f32x4;
struct alignas(16) US8 { unsigned short u[8]; };

__device__ inline float waveReduceSum(float v) {
#pragma unroll
    for (int m = 32; m >= 1; m >>= 1) v += __shfl_xor(v, m, 64);
    return v;
}
__device__ inline unsigned short f2bf(float f) {
    uint32_t u = __float_as_uint(f);
    return (unsigned short)((u + 0x7FFFu + ((u >> 16) & 1u)) >> 16);
}
__device__ inline void gload_lds16(const void* g, void* l) {
    __builtin_amdgcn_global_load_lds(
        (const __attribute__((address_space(1))) uint32_t*)g,
        (__attribute__((address_space(3))) uint32_t*)l, 16, 0, 0);
}

// --- K1: fused normalize + per-class centroid (block per class, 16 waves) ---
__global__ __launch_bounds__(1024) void k_centroid(
        const float* __restrict__ emb, const int* __restrict__ y,
        const float* __restrict__ wptr, unsigned short* __restrict__ ebf,
        unsigned short* __restrict__ csum_bf, float* __restrict__ normsq,
        float* __restrict__ colscale, int* __restrict__ counts, int N) {
    __shared__ float part[16][512];
    __shared__ float red[512];
    __shared__ int cnts[16];
    int c = blockIdx.x;
    int tid = threadIdx.x, l = tid & 63, w = tid >> 6;
    int chunk = N >> 4;                       // rows per wave (1024)
    float facc[8] = {0.f, 0.f, 0.f, 0.f, 0.f, 0.f, 0.f, 0.f};
    int cnt = 0;
    int iend = (w + 1) * chunk;
    int i0 = w * chunk;
    int4 y4 = *reinterpret_cast<const int4*>(y + i0 + l * 4);
    for (; i0 < iend; i0 += 256) {
        int4 cy = y4;
        if (i0 + 256 < iend)                  // prefetch next y tile
            y4 = *reinterpret_cast<const int4*>(y + i0 + 256 + l * 4);
#pragma unroll
        for (int comp = 0; comp < 4; ++comp) {
            int yv = (comp == 0) ? cy.x : (comp == 1) ? cy.y : (comp == 2) ? cy.z : cy.w;
            unsigned long long m = __ballot(yv == c);
            cnt += (int)__popcll(m);
            while (m) {                        // wave-uniform mask
                int b = __builtin_ctzll(m);
                m &= m - 1;
                int r = i0 + 4 * b + comp;
                const float4* pr = reinterpret_cast<const float4*>(emb + (size_t)r * 512);
                float4 v0 = pr[l * 2], v1 = pr[l * 2 + 1];
                float s = v0.x * v0.x + v0.y * v0.y + v0.z * v0.z + v0.w * v0.w
                        + v1.x * v1.x + v1.y * v1.y + v1.z * v1.z + v1.w * v1.w;
                s = waveReduceSum(s);
                float inv = 1.0f / fmaxf(sqrtf(s), 1e-12f);
                float e0 = v0.x * inv, e1 = v0.y * inv, e2 = v0.z * inv, e3 = v0.w * inv;
                float e4 = v1.x * inv, e5 = v1.y * inv, e6 = v1.z * inv, e7 = v1.w * inv;
                US8 t;
                t.u[0] = f2bf(e0); t.u[1] = f2bf(e1); t.u[2] = f2bf(e2); t.u[3] = f2bf(e3);
                t.u[4] = f2bf(e4); t.u[5] = f2bf(e5); t.u[6] = f2bf(e6); t.u[7] = f2bf(e7);
                *reinterpret_cast<US8*>(ebf + (size_t)r * 512 + l * 8) = t;
                facc[0] += e0; facc[1] += e1; facc[2] += e2; facc[3] += e3;
                facc[4] += e4; facc[5] += e5; facc[6] += e6; facc[7] += e7;
            }
        }
    }
    *reinterpret_cast<float4*>(&part[w][l * 8]) =
        make_float4(facc[0], facc[1], facc[2], facc[3]);
    *reinterpret_cast<float4*>(&part[w][l * 8 + 4]) =
        make_float4(facc[4], facc[5], facc[6], facc[7]);
    if (l == 0) cnts[w] = cnt;
    __syncthreads();
    if (tid < 512) {
        float s = 0.f;
#pragma unroll
        for (int r = 0; r < 16; ++r) s += part[r][tid];
        csum_bf[(size_t)c * 512 + tid] = f2bf(s);
        red[tid] = s * s;
    }
    __syncthreads();
    for (int o = 256; o >= 1; o >>= 1) {
        if (tid < o) red[tid] += red[tid + o];
        __syncthreads();
    }
    if (tid == 0) {
        int ct = 0;
#pragma unroll
        for (int r = 0; r < 16; ++r) ct += cnts[r];
        counts[c] = ct;
        float nsq = red[0];
        normsq[c] = nsq;
        colscale[c] = wptr[0] / fmaxf(sqrtf(nsq), (float)ct * 1e-8f);
    }
}

// --- K2: GEMM (64 rows x 256 cols per block, 8 waves, dbuf gload_lds) ---
#define NKT 8

__global__ __launch_bounds__(512) void k_gemm(
        const unsigned short* __restrict__ ebf, const unsigned short* __restrict__ csum_bf,
        const int* __restrict__ y, const float* __restrict__ colscale,
        const float* __restrict__ normsq, const int* __restrict__ counts,
        const float* __restrict__ wptr, const float* __restrict__ bptr,
        float* __restrict__ colpart, float* __restrict__ selfpart, int C) {
    __shared__ __align__(16) unsigned short As[2][8 * 512];     // 2 x 8 KB
    __shared__ __align__(16) unsigned short Bs[2][32 * 512];    // 2 x 32 KB
    __shared__ float colsum[256];
    __shared__ float selfred[8];

    const int tid = threadIdx.x;
    const int l = tid & 63;
    const int w = tid >> 6;
    const int bx = blockIdx.x;
    const int r0 = bx * 64;
    const int rsub = l >> 2;
    const int kcs = ((l & 3) ^ ((l >> 3) & 3)) * 8;

    const unsigned short* srcA = ebf + (size_t)(r0 + (w & 3) * 16 + rsub) * 512
                               + (w >> 2) * 32 + kcs;
    const unsigned short* srcB[4];
#pragma unroll
    for (int i = 0; i < 4; ++i) {
        int st = w * 4 + i;
        srcB[i] = csum_bf + (size_t)((st & 15) * 16 + rsub) * 512 + (st >> 4) * 32 + kcs;
    }
    const int fro = (l & 15) * 32 + (((l >> 4) ^ ((l >> 1) & 3)) * 8);

    f32x4 acc[4][2];
#pragma unroll
    for (int m = 0; m < 4; ++m)
#pragma unroll
        for (int n = 0; n < 2; ++n) acc[m][n] = (f32x4){0.f, 0.f, 0.f, 0.f};

    gload_lds16(srcA, &As[0][w * 512]);
#pragma unroll
    for (int i = 0; i < 4; ++i) gload_lds16(srcB[i], &Bs[0][(w * 4 + i) * 512]);
    __syncthreads();

    int cur = 0;
    for (int kt = 0; kt < NKT; ++kt) {
        if (kt + 1 < NKT) {
            gload_lds16(srcA + (kt + 1) * 64, &As[cur ^ 1][w * 512]);
#pragma unroll
            for (int i = 0; i < 4; ++i)
                gload_lds16(srcB[i] + (kt + 1) * 64, &Bs[cur ^ 1][(w * 4 + i) * 512]);
        }
#pragma unroll
        for (int h = 0; h < 2; ++h) {
            bf16x8 af[4];
#pragma unroll
            for (int m = 0; m < 4; ++m)
                af[m] = *reinterpret_cast<const bf16x8*>(&As[cur][(h * 4 + m) * 512 + fro]);
#pragma unroll
            for (int n = 0; n < 2; ++n) {
                bf16x8 bv = *reinterpret_cast<const bf16x8*>(
                    &Bs[cur][(h * 16 + w * 2 + n) * 512 + fro]);
#pragma unroll
                for (int m = 0; m < 4; ++m)
                    acc[m][n] = __builtin_amdgcn_mfma_f32_16x16x32_bf16(af[m], bv, acc[m][n], 0, 0, 0);
            }
        }
        __syncthreads();
        cur ^= 1;
    }

    // epilogue: C/D layout col=lane&15, row=(lane>>4)*4+j; wave w -> cols w*32..+31
    float bv = bptr[0], wv = wptr[0];
    int lcol = l & 15, lrow4 = (l >> 4) * 4;
    float cs[2], nsq[2], cm1[2]; int cls[2];
#pragma unroll
    for (int n = 0; n < 2; ++n) {
        int c = w * 32 + n * 16 + lcol;
        cls[n] = c; cs[n] = colscale[c]; nsq[n] = normsq[c];
        cm1[n] = (float)(counts[c] - 1);
    }
    float colacc[2] = {0.f, 0.f};
    float selfacc = 0.f;
#pragma unroll
    for (int m = 0; m < 4; ++m) {
#pragma unroll
        for (int j = 0; j < 4; ++j) {
            int row = r0 + m * 16 + lrow4 + j;
            int yc = y[row];
#pragma unroll
            for (int n = 0; n < 2; ++n) {
                float dot = acc[m][n][j];
                float logit;
                if (yc == cls[n]) {
                    float un2 = fmaxf(nsq[n] - 2.f * dot + 1.f, 0.f);
                    float denom = fmaxf(sqrtf(un2), cm1[n] * 1e-8f);
                    logit = wv * (dot - 1.f) / denom + bv;
                    selfacc += logit;
                } else {
                    logit = dot * cs[n] + bv;
                }
                colacc[n] += __expf(logit);
            }
        }
    }
#pragma unroll
    for (int n = 0; n < 2; ++n) {
        float v = colacc[n];
        v += __shfl_xor(v, 16, 64);
        v += __shfl_xor(v, 32, 64);
        colacc[n] = v;
    }
    selfacc = waveReduceSum(selfacc);
    if (l < 16) {
#pragma unroll
        for (int n = 0; n < 2; ++n) colsum[w * 32 + n * 16 + l] = colacc[n];
    }
    if (l == 0) selfred[w] = selfacc;
    __syncthreads();
    if (tid < 256)
        colpart[(size_t)bx * 256 + tid] = colsum[tid];
    if (tid == 0)
        selfpart[bx] = selfred[0] + selfred[1] + selfred[2] + selfred[3]
                     + selfred[4] + selfred[5] + selfred[6] + selfred[7];
}

// --- K3: per-class reduce -> contrib[c] = counts[c]*log(sum over row tiles) ---
__global__ __launch_bounds__(64) void k_colreduce(
        const float* __restrict__ colpart, const int* __restrict__ counts,
        float* __restrict__ contrib, int nbx, int C) {
    int c = blockIdx.x, l = threadIdx.x;
    float s = 0.f;
    for (int i = l; i < nbx; i += 64) s += colpart[(size_t)i * C + c];
    s = waveReduceSum(s);
    if (l == 0) contrib[c] = (float)counts[c] * logf(s);
}

// --- K4: finalize: sum contribs minus self partials ---
__global__ __launch_bounds__(256) void k_final(
        const float* __restrict__ contrib, const float* __restrict__ selfpart,
        float* __restrict__ out, int nbx, int C) {
    __shared__ float lds[256];
    int tid = threadIdx.x;
    float v = (tid < C) ? contrib[tid] : 0.f;
    for (int i = tid; i < nbx; i += 256) v -= selfpart[i];
    lds[tid] = v;
    __syncthreads();
    for (int o = 128; o >= 1; o >>= 1) {
        if (tid < o) lds[tid] += lds[tid + o];
        __syncthreads();
    }
    if (tid == 0) out[0] = lds[0];
}

extern "C" void kernel_launch(void* const* d_in, const int* in_sizes, int n_in,
                              void* d_out, int out_size, void* d_ws, size_t ws_size,
                              hipStream_t stream) {
    const float* emb  = (const float*)d_in[0];
    const int*   y    = (const int*)d_in[1];
    const float* wptr = (const float*)d_in[2];
    const float* bptr = (const float*)d_in[3];
    float* out = (float*)d_out;
    int N = in_sizes[1];                      // 16384
    const int C = 256;
    int nbx = N / 64;                         // 256

    unsigned short* ebf     = (unsigned short*)d_ws;                 // N*512 bf16
    unsigned short* csum_bf = ebf + (size_t)N * 512;                 // C*512 bf16
    float* colpart  = (float*)(csum_bf + (size_t)C * 512);           // nbx*C
    float* selfpart = colpart + (size_t)nbx * C;                     // nbx
    float* normsq   = selfpart + nbx;                                // C
    float* colscale = normsq + C;                                    // C
    int*   counts   = (int*)(colscale + C);                          // C
    float* contrib  = (float*)(counts + C);                          // C

    k_centroid <<<C, 1024, 0, stream>>>(emb, y, wptr, ebf, csum_bf, normsq,
                                        colscale, counts, N);
    k_gemm     <<<nbx, 512, 0, stream>>>(ebf, csum_bf, y, colscale, normsq, counts,
                                         wptr, bptr, colpart, selfpart, C);
    k_colreduce<<<C, 64, 0, stream>>>(colpart, counts, contrib, nbx, C);
    k_final    <<<1, 256, 0, stream>>>(contrib, selfpart, out, nbx, C);
}

// Round 16
// 33.626 us; speedup vs baseline: 1.5231x; 1.0599x over previous
//
#include <hip/hip_runtime.h>
#include <math.h>
#include <stdint.h>

// GE2E loss on MI355X — 4-kernel pipeline. No memsets, no fences, no atomics.
// out = sum_k counts[k]*log(sum_j exp(S[j,k])) - sum_i logit_self[i]
// Logits <= w*1+b = 5 -> exp without max-subtraction is safe in fp32.
// K1 (1024 thr, block=class): ballot-gather centroid; writes inv_norm (NOT ebf:
//     the 16MB bf16 intermediate was pure write+reread traffic).
// K2 (512 thr): MFMA GEMM; A reg-staged from fp32 emb (L3-resident after K1) with
//     on-the-fly x inv_norm + bf16 convert, ds_write AFTER compute (T14 split);
//     B via gload_lds from csum_bf. Same swizzled LDS layout as the gload path.
// K3 (256 blk): per-class colpart reduce -> contrib[c].  K4 (1 blk): final sum.
// Self logit: u = csum_y - e; dot(e,u)=dot-1; |u|^2 = nsq - 2*dot + 1.
// LESSON (r5/r14): never single-block-reduce the 256KB colpart (~13us on one CU).
// LESSON (r9): no per-block __threadfence/ticket tails (L2 writeback storm).

typedef __attribute__((ext_vector_type(8))) short bf16x8;
typedef __attribute__((ext_vector_type(4))) float f32x4;
struct alignas(16) US8 { unsigned short u[8]; };

__device__ inline float waveReduceSum(float v) {
#pragma unroll
    for (int m = 32; m >= 1; m >>= 1) v += __shfl_xor(v, m, 64);
    return v;
}
__device__ inline unsigned short f2bf(float f) {
    uint32_t u = __float_as_uint(f);
    return (unsigned short)((u + 0x7FFFu + ((u >> 16) & 1u)) >> 16);
}
__device__ inline void gload_lds16(const void* g, void* l) {
    __builtin_amdgcn_global_load_lds(
        (const __attribute__((address_space(1))) uint32_t*)g,
        (__attribute__((address_space(3))) uint32_t*)l, 16, 0, 0);
}

// --- K1: fused normalize + per-class centroid (block per class, 16 waves) ---
__global__ __launch_bounds__(1024) void k_centroid(
        const float* __restrict__ emb, const int* __restrict__ y,
        const float* __restrict__ wptr, float* __restrict__ inv_norm,
        unsigned short* __restrict__ csum_bf, float* __restrict__ normsq,
        float* __restrict__ colscale, int* __restrict__ counts, int N) {
    __shared__ float part[16][512];
    __shared__ float red[512];
    __shared__ int cnts[16];
    int c = blockIdx.x;
    int tid = threadIdx.x, l = tid & 63, w = tid >> 6;
    int chunk = N >> 4;                       // rows per wave (1024)
    float facc[8] = {0.f, 0.f, 0.f, 0.f, 0.f, 0.f, 0.f, 0.f};
    int cnt = 0;
    int iend = (w + 1) * chunk;
    int i0 = w * chunk;
    int4 y4 = *reinterpret_cast<const int4*>(y + i0 + l * 4);
    for (; i0 < iend; i0 += 256) {
        int4 cy = y4;
        if (i0 + 256 < iend)                  // prefetch next y tile
            y4 = *reinterpret_cast<const int4*>(y + i0 + 256 + l * 4);
#pragma unroll
        for (int comp = 0; comp < 4; ++comp) {
            int yv = (comp == 0) ? cy.x : (comp == 1) ? cy.y : (comp == 2) ? cy.z : cy.w;
            unsigned long long m = __ballot(yv == c);
            cnt += (int)__popcll(m);
            while (m) {                        // wave-uniform mask
                int b = __builtin_ctzll(m);
                m &= m - 1;
                int r = i0 + 4 * b + comp;
                const float4* pr = reinterpret_cast<const float4*>(emb + (size_t)r * 512);
                float4 v0 = pr[l * 2], v1 = pr[l * 2 + 1];
                float s = v0.x * v0.x + v0.y * v0.y + v0.z * v0.z + v0.w * v0.w
                        + v1.x * v1.x + v1.y * v1.y + v1.z * v1.z + v1.w * v1.w;
                s = waveReduceSum(s);
                float inv = 1.0f / fmaxf(sqrtf(s), 1e-12f);
                if (l == 0) inv_norm[r] = inv;
                facc[0] += v0.x * inv; facc[1] += v0.y * inv;
                facc[2] += v0.z * inv; facc[3] += v0.w * inv;
                facc[4] += v1.x * inv; facc[5] += v1.y * inv;
                facc[6] += v1.z * inv; facc[7] += v1.w * inv;
            }
        }
    }
    *reinterpret_cast<float4*>(&part[w][l * 8]) =
        make_float4(facc[0], facc[1], facc[2], facc[3]);
    *reinterpret_cast<float4*>(&part[w][l * 8 + 4]) =
        make_float4(facc[4], facc[5], facc[6], facc[7]);
    if (l == 0) cnts[w] = cnt;
    __syncthreads();
    if (tid < 512) {
        float s = 0.f;
#pragma unroll
        for (int r = 0; r < 16; ++r) s += part[r][tid];
        csum_bf[(size_t)c * 512 + tid] = f2bf(s);
        red[tid] = s * s;
    }
    __syncthreads();
    for (int o = 256; o >= 1; o >>= 1) {
        if (tid < o) red[tid] += red[tid + o];
        __syncthreads();
    }
    if (tid == 0) {
        int ct = 0;
#pragma unroll
        for (int r = 0; r < 16; ++r) ct += cnts[r];
        counts[c] = ct;
        float nsq = red[0];
        normsq[c] = nsq;
        colscale[c] = wptr[0] / fmaxf(sqrtf(nsq), (float)ct * 1e-8f);
    }
}

// --- K2: GEMM (64 rows x 256 cols per block, 8 waves); A reg-staged from emb ---
#define NKT 8

__global__ __launch_bounds__(512) void k_gemm(
        const float* __restrict__ emb, const float* __restrict__ inv_norm,
        const unsigned short* __restrict__ csum_bf,
        const int* __restrict__ y, const float* __restrict__ colscale,
        const float* __restrict__ normsq, const int* __restrict__ counts,
        const float* __restrict__ wptr, const float* __restrict__ bptr,
        float* __restrict__ colpart, float* __restrict__ selfpart, int C) {
    __shared__ __align__(16) unsigned short As[2][8 * 512];     // 2 x 8 KB
    __shared__ __align__(16) unsigned short Bs[2][32 * 512];    // 2 x 32 KB
    __shared__ float colsum[256];
    __shared__ float selfred[8];

    const int tid = threadIdx.x;
    const int l = tid & 63;
    const int w = tid >> 6;
    const int bx = blockIdx.x;
    const int r0 = bx * 64;
    const int rsub = l >> 2;
    const int kcs = ((l & 3) ^ ((l >> 3) & 3)) * 8;   // swizzled k-chunk (elements)

    // A: thread owns one row for all K-tiles; same swizzled layout as gload path:
    // LDS slot (rr=l>>2, kc0=l&3) <- source k-chunk kc0 ^ ((rr>>1)&3).
    const int arow = r0 + (w & 3) * 16 + rsub;
    const float* srcA = emb + (size_t)arow * 512 + (w >> 2) * 32 + kcs;
    const float invA = inv_norm[arow];
    // B: 32 subtiles (kh*16 + colblk); wave w stages subtiles w*4..w*4+3.
    const unsigned short* srcB[4];
#pragma unroll
    for (int i = 0; i < 4; ++i) {
        int st = w * 4 + i;
        srcB[i] = csum_bf + (size_t)((st & 15) * 16 + rsub) * 512 + (st >> 4) * 32 + kcs;
    }
    const int fro = (l & 15) * 32 + (((l >> 4) ^ ((l >> 1) & 3)) * 8);

    f32x4 acc[4][2];
#pragma unroll
    for (int m = 0; m < 4; ++m)
#pragma unroll
        for (int n = 0; n < 2; ++n) acc[m][n] = (f32x4){0.f, 0.f, 0.f, 0.f};

    // prologue: stage kt=0
    {
        float4 a0 = *reinterpret_cast<const float4*>(srcA);
        float4 a1 = *reinterpret_cast<const float4*>(srcA + 4);
        US8 t;
        t.u[0] = f2bf(a0.x * invA); t.u[1] = f2bf(a0.y * invA);
        t.u[2] = f2bf(a0.z * invA); t.u[3] = f2bf(a0.w * invA);
        t.u[4] = f2bf(a1.x * invA); t.u[5] = f2bf(a1.y * invA);
        t.u[6] = f2bf(a1.z * invA); t.u[7] = f2bf(a1.w * invA);
        *reinterpret_cast<US8*>(&As[0][w * 512 + l * 8]) = t;
    }
#pragma unroll
    for (int i = 0; i < 4; ++i) gload_lds16(srcB[i], &Bs[0][(w * 4 + i) * 512]);
    __syncthreads();

    int cur = 0;
    for (int kt = 0; kt < NKT; ++kt) {
        float4 a0, a1;
        const bool hasNext = (kt + 1 < NKT);
        if (hasNext) {
            a0 = *reinterpret_cast<const float4*>(srcA + (kt + 1) * 64);      // issue early
            a1 = *reinterpret_cast<const float4*>(srcA + (kt + 1) * 64 + 4);
#pragma unroll
            for (int i = 0; i < 4; ++i)
                gload_lds16(srcB[i] + (kt + 1) * 64, &Bs[cur ^ 1][(w * 4 + i) * 512]);
        }
#pragma unroll
        for (int h = 0; h < 2; ++h) {
            bf16x8 af[4];
#pragma unroll
            for (int m = 0; m < 4; ++m)
                af[m] = *reinterpret_cast<const bf16x8*>(&As[cur][(h * 4 + m) * 512 + fro]);
#pragma unroll
            for (int n = 0; n < 2; ++n) {
                bf16x8 bv = *reinterpret_cast<const bf16x8*>(
                    &Bs[cur][(h * 16 + w * 2 + n) * 512 + fro]);
#pragma unroll
                for (int m = 0; m < 4; ++m)
                    acc[m][n] = __builtin_amdgcn_mfma_f32_16x16x32_bf16(af[m], bv, acc[m][n], 0, 0, 0);
            }
        }
        if (hasNext) {   // convert+write after compute (loads hid under MFMA phase)
            US8 t;
            t.u[0] = f2bf(a0.x * invA); t.u[1] = f2bf(a0.y * invA);
            t.u[2] = f2bf(a0.z * invA); t.u[3] = f2bf(a0.w * invA);
            t.u[4] = f2bf(a1.x * invA); t.u[5] = f2bf(a1.y * invA);
            t.u[6] = f2bf(a1.z * invA); t.u[7] = f2bf(a1.w * invA);
            *reinterpret_cast<US8*>(&As[cur ^ 1][w * 512 + l * 8]) = t;
        }
        __syncthreads();
        cur ^= 1;
    }

    // epilogue: C/D layout col=lane&15, row=(lane>>4)*4+j; wave w -> cols w*32..+31
    float bv = bptr[0], wv = wptr[0];
    int lcol = l & 15, lrow4 = (l >> 4) * 4;
    float cs[2], nsq[2], cm1[2]; int cls[2];
#pragma unroll
    for (int n = 0; n < 2; ++n) {
        int c = w * 32 + n * 16 + lcol;
        cls[n] = c; cs[n] = colscale[c]; nsq[n] = normsq[c];
        cm1[n] = (float)(counts[c] - 1);
    }
    float colacc[2] = {0.f, 0.f};
    float selfacc = 0.f;
#pragma unroll
    for (int m = 0; m < 4; ++m) {
#pragma unroll
        for (int j = 0; j < 4; ++j) {
            int row = r0 + m * 16 + lrow4 + j;
            int yc = y[row];
#pragma unroll
            for (int n = 0; n < 2; ++n) {
                float dot = acc[m][n][j];
                float logit;
                if (yc == cls[n]) {
                    float un2 = fmaxf(nsq[n] - 2.f * dot + 1.f, 0.f);
                    float denom = fmaxf(sqrtf(un2), cm1[n] * 1e-8f);
                    logit = wv * (dot - 1.f) / denom + bv;
                    selfacc += logit;
                } else {
                    logit = dot * cs[n] + bv;
                }
                colacc[n] += __expf(logit);
            }
        }
    }
#pragma unroll
    for (int n = 0; n < 2; ++n) {
        float v = colacc[n];
        v += __shfl_xor(v, 16, 64);
        v += __shfl_xor(v, 32, 64);
        colacc[n] = v;
    }
    selfacc = waveReduceSum(selfacc);
    if (l < 16) {
#pragma unroll
        for (int n = 0; n < 2; ++n) colsum[w * 32 + n * 16 + l] = colacc[n];
    }
    if (l == 0) selfred[w] = selfacc;
    __syncthreads();
    if (tid < 256)
        colpart[(size_t)bx * 256 + tid] = colsum[tid];
    if (tid == 0)
        selfpart[bx] = selfred[0] + selfred[1] + selfred[2] + selfred[3]
                     + selfred[4] + selfred[5] + selfred[6] + selfred[7];
}

// --- K3: per-class reduce -> contrib[c] = counts[c]*log(sum over row tiles) ---
__global__ __launch_bounds__(64) void k_colreduce(
        const float* __restrict__ colpart, const int* __restrict__ counts,
        float* __restrict__ contrib, int nbx, int C) {
    int c = blockIdx.x, l = threadIdx.x;
    float s = 0.f;
    for (int i = l; i < nbx; i += 64) s += colpart[(size_t)i * C + c];
    s = waveReduceSum(s);
    if (l == 0) contrib[c] = (float)counts[c] * logf(s);
}

// --- K4: finalize: sum contribs minus self partials ---
__global__ __launch_bounds__(256) void k_final(
        const float* __restrict__ contrib, const float* __restrict__ selfpart,
        float* __restrict__ out, int nbx, int C) {
    __shared__ float lds[256];
    int tid = threadIdx.x;
    float v = (tid < C) ? contrib[tid] : 0.f;
    for (int i = tid; i < nbx; i += 256) v -= selfpart[i];
    lds[tid] = v;
    __syncthreads();
    for (int o = 128; o >= 1; o >>= 1) {
        if (tid < o) lds[tid] += lds[tid + o];
        __syncthreads();
    }
    if (tid == 0) out[0] = lds[0];
}

extern "C" void kernel_launch(void* const* d_in, const int* in_sizes, int n_in,
                              void* d_out, int out_size, void* d_ws, size_t ws_size,
                              hipStream_t stream) {
    const float* emb  = (const float*)d_in[0];
    const int*   y    = (const int*)d_in[1];
    const float* wptr = (const float*)d_in[2];
    const float* bptr = (const float*)d_in[3];
    float* out = (float*)d_out;
    int N = in_sizes[1];                      // 16384
    const int C = 256;
    int nbx = N / 64;                         // 256

    float* inv_norm = (float*)d_ws;                                  // N
    unsigned short* csum_bf = (unsigned short*)(inv_norm + N);       // C*512 bf16
    float* colpart  = (float*)(csum_bf + (size_t)C * 512);           // nbx*C
    float* selfpart = colpart + (size_t)nbx * C;                     // nbx
    float* normsq   = selfpart + nbx;                                // C
    float* colscale = normsq + C;                                    // C
    int*   counts   = (int*)(colscale + C);                          // C
    float* contrib  = (float*)(counts + C);                          // C

    k_centroid <<<C, 1024, 0, stream>>>(emb, y, wptr, inv_norm, csum_bf, normsq,
                                        colscale, counts, N);
    k_gemm     <<<nbx, 512, 0, stream>>>(emb, inv_norm, csum_bf, y, colscale, normsq,
                                         counts, wptr, bptr, colpart, selfpart, C);
    k_colreduce<<<C, 64, 0, stream>>>(colpart, counts, contrib, nbx, C);
    k_final    <<<1, 256, 0, stream>>>(contrib, selfpart, out, nbx, C);
}